// Round 16
// baseline (290.776 us; speedup 1.0000x reference)
//
#include <hip/hip_runtime.h>

// Problem constants
#define P_TOTAL   32768      // 8*64*64 patches
#define C_DIM     64         // patch dim / channels
#define N_ATOMS   512
#define K_SP      5
#define HW_DIM    4096       // 64*64
#define OUT_ZDL   2097152    // 8*64*64*64
#define OUT_LOSS  2097152
#define OUT_COEFF 2097153
#define COEFF_N   16777216   // 512*32768

// ---------------- zero the loss + coeffs region ----------------
__global__ void zero_tail(float* __restrict__ out) {
    float4* base = reinterpret_cast<float4*>(out + OUT_LOSS);
    const unsigned n4 = 4194304;  // 16777216/4
    unsigned stride = gridDim.x * blockDim.x;
    for (unsigned i = blockIdx.x * blockDim.x + threadIdx.x; i < n4; i += stride)
        base[i] = float4{0.f, 0.f, 0.f, 0.f};
    if (blockIdx.x == 0 && threadIdx.x == 0)
        out[OUT_LOSS + 16777216] = 0.f;
}

// ---------------- prep: G (f64) + Gf (f32) + Dt (f32) ----------------
__global__ void prep_kernel(const float* __restrict__ D,
                            double* __restrict__ G,
                            float* __restrict__ Gf,
                            float* __restrict__ Dt) {
    int tid = blockIdx.x * blockDim.x + threadIdx.x;  // 1024*256 = 262144
    int i = tid >> 9;
    int j = tid & 511;
    double s = 0.0;
    #pragma unroll
    for (int m = 0; m < 64; ++m)
        s += (double)D[m * 512 + i] * (double)D[m * 512 + j];
    if (i == j) s += 1e-5;
    G[(size_t)i * 512 + j] = s;
    Gf[(size_t)i * 512 + j] = (float)s;
    if (tid < N_ATOMS * C_DIM) {
        int n = tid >> 6, m = tid & 63;
        Dt[n * 64 + m] = D[m * 512 + n];
    }
}

// ---------------- h_bar GEMM, f32: 4 patches/wave (32 acc VGPRs) ----------
__launch_bounds__(256)
__global__ void hbar_kernel(const float* __restrict__ ze,
                            const float* __restrict__ D,
                            float* __restrict__ H) {
    __shared__ float sp[16][64];
    const int tid = threadIdx.x;
    const int p0  = blockIdx.x * 16;

    {
        const int i = tid & 15, c0 = tid >> 4;  // c0 = 0..15
        const int p = p0 + i, b = p >> 12, hw = p & 4095;
        #pragma unroll
        for (int r = 0; r < 4; ++r) {
            int c = c0 * 4 + r;
            sp[i][c] = ze[(size_t)(b * 64 + c) * 4096 + hw];
        }
    }
    __syncthreads();

    const int wave = tid >> 6, lane = tid & 63;
    const int pw = wave * 4;

    float acc[4][8];
    #pragma unroll
    for (int pi = 0; pi < 4; ++pi)
        #pragma unroll
        for (int j = 0; j < 8; ++j) acc[pi][j] = 0.f;

    for (int c = 0; c < 64; ++c) {
        const float4 d0 = *reinterpret_cast<const float4*>(D + c * 512 + lane * 8);
        const float4 d1 = *reinterpret_cast<const float4*>(D + c * 512 + lane * 8 + 4);
        #pragma unroll
        for (int pi = 0; pi < 4; ++pi) {
            const float pc = sp[pw + pi][c];
            acc[pi][0] += pc * d0.x; acc[pi][1] += pc * d0.y;
            acc[pi][2] += pc * d0.z; acc[pi][3] += pc * d0.w;
            acc[pi][4] += pc * d1.x; acc[pi][5] += pc * d1.y;
            acc[pi][6] += pc * d1.z; acc[pi][7] += pc * d1.w;
        }
    }

    #pragma unroll
    for (int pi = 0; pi < 4; ++pi) {
        float* Hp = H + (size_t)(p0 + pw + pi) * 512 + lane * 8;
        reinterpret_cast<float4*>(Hp)[0] = float4{acc[pi][0], acc[pi][1], acc[pi][2], acc[pi][3]};
        reinterpret_cast<float4*>(Hp)[1] = float4{acc[pi][4], acc[pi][5], acc[pi][6], acc[pi][7]};
    }
}

// ---------------- OMP iterations: ONE WAVE PER BLOCK (64 thr) ----------------
// f32 h/argmax/residual; f64 Gram solve. Lane owns atoms lane*8 + j.
// No LDS, no __syncthreads — loss partial written per wave.
__launch_bounds__(64)
__global__ void omp2_kernel(const float* __restrict__ ze,
                            const float* __restrict__ H,
                            const double* __restrict__ G,
                            const float* __restrict__ Gf,
                            const float* __restrict__ Dt,
                            float* __restrict__ out,
                            double* __restrict__ lpart) {
    const int lane = threadIdx.x & 63;
    const int p    = blockIdx.x;
    const int b    = p >> 12;
    const int hw   = p & 4095;

    const float pe = ze[(size_t)(b * 64 + lane) * 4096 + hw];

    // load h_bar (f32, 8 consecutive per lane)
    float hb[8], h[8];
    {
        const float4* Hp = reinterpret_cast<const float4*>(H + (size_t)p * 512 + lane * 8);
        float4 t0 = Hp[0], t1 = Hp[1];
        hb[0] = t0.x; hb[1] = t0.y; hb[2] = t0.z; hb[3] = t0.w;
        hb[4] = t1.x; hb[5] = t1.y; hb[6] = t1.z; hb[7] = t1.w;
    }
    #pragma unroll
    for (int j = 0; j < 8; ++j) h[j] = hb[j];

    unsigned mask = 0;
    int    a[5];
    double rhs[5];
    double x[5];

    #pragma unroll
    for (int k = 0; k < K_SP; ++k) {
        // ---- local argmax of |h| (f32, skip masked), lowest-n tie-break ----
        float bv = -1.0f; int bn = 0x7fffffff;
        #pragma unroll
        for (int j = 0; j < 8; ++j) {
            float av = fabsf(h[j]);
            bool ok = !((mask >> j) & 1u);
            int n = lane * 8 + j;
            if (ok && (av > bv || (av == bv && n < bn))) { bv = av; bn = n; }
        }
        // ---- wave argmax reduce ----
        #pragma unroll
        for (int off = 32; off > 0; off >>= 1) {
            float ov = __shfl_xor(bv, off);
            int   on = __shfl_xor(bn, off);
            if (ov > bv || (ov == bv && on < bn)) { bv = ov; bn = on; }
        }
        a[k] = bn;
        {
            const int src = bn >> 3, jj = bn & 7;
            float v = 0.f;
            #pragma unroll
            for (int j = 0; j < 8; ++j) if (j == jj) v = hb[j];
            rhs[k] = (double)__shfl(v, src);
            if (lane == src) mask |= (1u << jj);
        }

        // ---- solve (k+1)x(k+1) Gram system in f64, replicated on all lanes ----
        double T[5][5], y[5];
        #pragma unroll
        for (int i = 0; i <= k; ++i) {
            #pragma unroll
            for (int j2 = 0; j2 <= k; ++j2)
                T[i][j2] = G[(size_t)a[i] * 512 + a[j2]];
            y[i] = rhs[i];
        }
        #pragma unroll
        for (int col = 0; col <= k; ++col) {
            double inv = 1.0 / T[col][col];
            #pragma unroll
            for (int r = col + 1; r <= k; ++r) {
                double f = T[r][col] * inv;
                #pragma unroll
                for (int cc = col; cc <= k; ++cc)
                    T[r][cc] -= f * T[col][cc];
                y[r] -= f * y[col];
            }
        }
        #pragma unroll
        for (int r = k; r >= 0; --r) {
            double s = y[r];
            #pragma unroll
            for (int cc = r + 1; cc <= k; ++cc) s -= T[r][cc] * x[cc];
            x[r] = s / T[r][r];
        }

        // ---- residual (f32): h = hb - sum_i xf_i * Gf[a_i] (i ascending) ----
        if (k < K_SP - 1) {
            #pragma unroll
            for (int j = 0; j < 8; ++j) h[j] = hb[j];
            #pragma unroll
            for (int i = 0; i <= k; ++i) {
                const float4* gr = reinterpret_cast<const float4*>(Gf + (size_t)a[i] * 512 + lane * 8);
                float4 g0 = gr[0], g1 = gr[1];
                const float xi = (float)x[i];
                h[0] -= xi * g0.x; h[1] -= xi * g0.y;
                h[2] -= xi * g0.z; h[3] -= xi * g0.w;
                h[4] -= xi * g1.x; h[5] -= xi * g1.y;
                h[6] -= xi * g1.z; h[7] -= xi * g1.w;
            }
        }
    }

    // ---- scatter coeffs.T ----
    if (lane == 0) {
        #pragma unroll
        for (int i = 0; i < K_SP; ++i)
            out[(size_t)OUT_COEFF + (size_t)a[i] * 32768 + p] = (float)x[i];
    }

    // ---- recon, z_dl_st ----
    double rc = 0.0;
    #pragma unroll
    for (int i = 0; i < K_SP; ++i)
        rc += x[i] * (double)Dt[(size_t)a[i] * 64 + lane];
    const float zd = (float)rc;
    out[(size_t)(b * 64 + lane) * 4096 + hw] = pe + (zd - pe);

    // ---- loss: wave reduce -> per-wave partial (no LDS, no barrier) ----
    const float df = zd - pe;
    double sq = (double)df * (double)df;
    #pragma unroll
    for (int off = 32; off > 0; off >>= 1)
        sq += __shfl_xor(sq, off);
    if (lane == 0) lpart[p] = sq;
}

// ---------------- final loss reduction: 32768 f64 partials -> out[OUT_LOSS] ----
__global__ void loss_reduce(const double* __restrict__ lpart,
                            float* __restrict__ out) {
    __shared__ double ls[4];
    const int tid = threadIdx.x, wave = tid >> 6, lane = tid & 63;
    double s = 0.0;
    for (int i = tid; i < P_TOTAL; i += 256) s += lpart[i];
    #pragma unroll
    for (int off = 32; off > 0; off >>= 1)
        s += __shfl_xor(s, off);
    if (lane == 0) ls[wave] = s;
    __syncthreads();
    if (tid == 0)
        out[OUT_LOSS] = (float)(((ls[0] + ls[1]) + (ls[2] + ls[3])) * (1.25 / 2097152.0));
}

extern "C" void kernel_launch(void* const* d_in, const int* in_sizes, int n_in,
                              void* d_out, int out_size, void* d_ws, size_t ws_size,
                              hipStream_t stream) {
    const float* ze = (const float*)d_in[0];   // (8,64,64,64) f32
    const float* D  = (const float*)d_in[1];   // (64,512) f32, unit-norm cols
    float* out = (float*)d_out;

    const size_t H_BYTES  = (size_t)P_TOTAL * 512 * 4;   // 67108864 (f32)
    const size_t G_BYTES  = (size_t)512 * 512 * 8;       // 2097152
    const size_t GF_BYTES = (size_t)512 * 512 * 4;       // 1048576
    const size_t DT_BYTES = (size_t)512 * 64 * 4;        // 131072

    float*  H  = (float*)d_ws;
    double* G  = (double*)((char*)d_ws + H_BYTES);
    float*  Gf = (float*)((char*)d_ws + H_BYTES + G_BYTES);
    float*  Dt = (float*)((char*)d_ws + H_BYTES + G_BYTES + GF_BYTES);
    double* LP = (double*)((char*)d_ws + H_BYTES + G_BYTES + GF_BYTES + DT_BYTES);

    zero_tail<<<2048, 256, 0, stream>>>(out);
    prep_kernel<<<1024, 256, 0, stream>>>(D, G, Gf, Dt);
    hbar_kernel<<<P_TOTAL / 16, 256, 0, stream>>>(ze, D, H);
    omp2_kernel<<<P_TOTAL, 64, 0, stream>>>(ze, H, G, Gf, Dt, out, LP);
    loss_reduce<<<1, 256, 0, stream>>>(LP, out);
}

// Round 17
// 263.333 us; speedup vs baseline: 1.1042x; 1.1042x over previous
//
#include <hip/hip_runtime.h>

// Problem constants
#define P_TOTAL   32768      // 8*64*64 patches
#define C_DIM     64         // patch dim / channels
#define N_ATOMS   512
#define K_SP      5
#define HW_DIM    4096       // 64*64
#define OUT_ZDL   2097152    // 8*64*64*64
#define OUT_LOSS  2097152
#define OUT_COEFF 2097153
#define COEFF_N   16777216   // 512*32768
#define NBLOCKS_OMP (P_TOTAL / 4)   // 8192

// setup_kernel block partition
#define NZ_BLOCKS   512                  // zero tail
#define PREP_BLOCKS 1024                 // G/Gf/Dt
#define HBAR_BLOCKS (P_TOTAL / 16)       // 2048, h_bar GEMM
#define SETUP_BLOCKS (NZ_BLOCKS + PREP_BLOCKS + HBAR_BLOCKS)  // 3584

// ---------------- fused setup: zero tail ∥ prep ∥ h_bar (independent) ------
// Block-range partition; divergence only at block granularity. The BW-bound
// zeroing overlaps the compute-bound h_bar GEMM within one dispatch.
__launch_bounds__(256)
__global__ void setup_kernel(const float* __restrict__ ze,
                             const float* __restrict__ D,
                             float* __restrict__ out,
                             double* __restrict__ G,
                             float* __restrict__ Gf,
                             float* __restrict__ Dt,
                             float* __restrict__ H) {
    __shared__ float sp[16][64];
    const int bid = blockIdx.x;

    if (bid < NZ_BLOCKS) {
        // ---- zero the loss + coeffs region (64 MB + 1 scalar) ----
        float4* base = reinterpret_cast<float4*>(out + OUT_LOSS);
        const unsigned nthr = NZ_BLOCKS * 256;
        for (unsigned i = bid * 256 + threadIdx.x; i < 4194304u; i += nthr)
            base[i] = float4{0.f, 0.f, 0.f, 0.f};
        if (bid == 0 && threadIdx.x == 0)
            out[OUT_LOSS + 16777216] = 0.f;
        return;
    }

    if (bid < NZ_BLOCKS + PREP_BLOCKS) {
        // ---- prep: G = D^T D + eps I (f64), Gf = f32(G), Dt = D^T ----
        int tid = (bid - NZ_BLOCKS) * 256 + threadIdx.x;  // 0..262143
        int i = tid >> 9;
        int j = tid & 511;
        double s = 0.0;
        #pragma unroll
        for (int m = 0; m < 64; ++m)
            s += (double)D[m * 512 + i] * (double)D[m * 512 + j];
        if (i == j) s += 1e-5;
        G[(size_t)i * 512 + j] = s;
        Gf[(size_t)i * 512 + j] = (float)s;
        if (tid < N_ATOMS * C_DIM) {
            int n = tid >> 6, m = tid & 63;
            Dt[n * 64 + m] = D[m * 512 + n];
        }
        return;
    }

    // ---- h_bar GEMM, f32: 4 waves x 4 patches, c ascending ----
    {
        const int tid = threadIdx.x;
        const int p0  = (bid - NZ_BLOCKS - PREP_BLOCKS) * 16;

        {
            const int i = tid & 15, c0 = tid >> 4;  // c0 = 0..15
            const int p = p0 + i, b = p >> 12, hw = p & 4095;
            #pragma unroll
            for (int r = 0; r < 4; ++r) {
                int c = c0 * 4 + r;
                sp[i][c] = ze[(size_t)(b * 64 + c) * 4096 + hw];
            }
        }
        __syncthreads();

        const int wave = tid >> 6, lane = tid & 63;
        const int pw = wave * 4;

        float acc[4][8];
        #pragma unroll
        for (int pi = 0; pi < 4; ++pi)
            #pragma unroll
            for (int j = 0; j < 8; ++j) acc[pi][j] = 0.f;

        for (int c = 0; c < 64; ++c) {
            const float4 d0 = *reinterpret_cast<const float4*>(D + c * 512 + lane * 8);
            const float4 d1 = *reinterpret_cast<const float4*>(D + c * 512 + lane * 8 + 4);
            #pragma unroll
            for (int pi = 0; pi < 4; ++pi) {
                const float pc = sp[pw + pi][c];
                acc[pi][0] += pc * d0.x; acc[pi][1] += pc * d0.y;
                acc[pi][2] += pc * d0.z; acc[pi][3] += pc * d0.w;
                acc[pi][4] += pc * d1.x; acc[pi][5] += pc * d1.y;
                acc[pi][6] += pc * d1.z; acc[pi][7] += pc * d1.w;
            }
        }

        #pragma unroll
        for (int pi = 0; pi < 4; ++pi) {
            float* Hp = H + (size_t)(p0 + pw + pi) * 512 + lane * 8;
            reinterpret_cast<float4*>(Hp)[0] = float4{acc[pi][0], acc[pi][1], acc[pi][2], acc[pi][3]};
            reinterpret_cast<float4*>(Hp)[1] = float4{acc[pi][4], acc[pi][5], acc[pi][6], acc[pi][7]};
        }
    }
}

// ---------------- OMP iterations: 4 waves/block, one wave per patch ---------
// (round-15 verified shape) f32 h/argmax/residual; f64 Gram solve.
__launch_bounds__(256)
__global__ void omp2_kernel(const float* __restrict__ ze,
                            const float* __restrict__ H,
                            const double* __restrict__ G,
                            const float* __restrict__ Gf,
                            const float* __restrict__ Dt,
                            float* __restrict__ out,
                            double* __restrict__ lpart) {
    __shared__ double lsum[4];
    const int wave = threadIdx.x >> 6;
    const int lane = threadIdx.x & 63;
    const int p    = blockIdx.x * 4 + wave;
    const int b    = p >> 12;
    const int hw   = p & 4095;

    const float pe = ze[(size_t)(b * 64 + lane) * 4096 + hw];

    // load h_bar (f32, 8 consecutive per lane)
    float hb[8], h[8];
    {
        const float4* Hp = reinterpret_cast<const float4*>(H + (size_t)p * 512 + lane * 8);
        float4 t0 = Hp[0], t1 = Hp[1];
        hb[0] = t0.x; hb[1] = t0.y; hb[2] = t0.z; hb[3] = t0.w;
        hb[4] = t1.x; hb[5] = t1.y; hb[6] = t1.z; hb[7] = t1.w;
    }
    #pragma unroll
    for (int j = 0; j < 8; ++j) h[j] = hb[j];

    unsigned mask = 0;
    int    a[5];
    double rhs[5];
    double x[5];

    #pragma unroll
    for (int k = 0; k < K_SP; ++k) {
        // ---- local argmax of |h| (f32, skip masked), lowest-n tie-break ----
        float bv = -1.0f; int bn = 0x7fffffff;
        #pragma unroll
        for (int j = 0; j < 8; ++j) {
            float av = fabsf(h[j]);
            bool ok = !((mask >> j) & 1u);
            int n = lane * 8 + j;
            if (ok && (av > bv || (av == bv && n < bn))) { bv = av; bn = n; }
        }
        // ---- wave argmax reduce ----
        #pragma unroll
        for (int off = 32; off > 0; off >>= 1) {
            float ov = __shfl_xor(bv, off);
            int   on = __shfl_xor(bn, off);
            if (ov > bv || (ov == bv && on < bn)) { bv = ov; bn = on; }
        }
        a[k] = bn;
        {
            const int src = bn >> 3, jj = bn & 7;
            float v = 0.f;
            #pragma unroll
            for (int j = 0; j < 8; ++j) if (j == jj) v = hb[j];
            rhs[k] = (double)__shfl(v, src);
            if (lane == src) mask |= (1u << jj);
        }

        // ---- solve (k+1)x(k+1) Gram system in f64, replicated on all lanes ----
        double T[5][5], y[5];
        #pragma unroll
        for (int i = 0; i <= k; ++i) {
            #pragma unroll
            for (int j2 = 0; j2 <= k; ++j2)
                T[i][j2] = G[(size_t)a[i] * 512 + a[j2]];
            y[i] = rhs[i];
        }
        #pragma unroll
        for (int col = 0; col <= k; ++col) {
            double inv = 1.0 / T[col][col];
            #pragma unroll
            for (int r = col + 1; r <= k; ++r) {
                double f = T[r][col] * inv;
                #pragma unroll
                for (int cc = col; cc <= k; ++cc)
                    T[r][cc] -= f * T[col][cc];
                y[r] -= f * y[col];
            }
        }
        #pragma unroll
        for (int r = k; r >= 0; --r) {
            double s = y[r];
            #pragma unroll
            for (int cc = r + 1; cc <= k; ++cc) s -= T[r][cc] * x[cc];
            x[r] = s / T[r][r];
        }

        // ---- residual (f32): h = hb - sum_i xf_i * Gf[a_i] (i ascending) ----
        if (k < K_SP - 1) {
            #pragma unroll
            for (int j = 0; j < 8; ++j) h[j] = hb[j];
            #pragma unroll
            for (int i = 0; i <= k; ++i) {
                const float4* gr = reinterpret_cast<const float4*>(Gf + (size_t)a[i] * 512 + lane * 8);
                float4 g0 = gr[0], g1 = gr[1];
                const float xi = (float)x[i];
                h[0] -= xi * g0.x; h[1] -= xi * g0.y;
                h[2] -= xi * g0.z; h[3] -= xi * g0.w;
                h[4] -= xi * g1.x; h[5] -= xi * g1.y;
                h[6] -= xi * g1.z; h[7] -= xi * g1.w;
            }
        }
    }

    // ---- scatter coeffs.T ----
    if (lane == 0) {
        #pragma unroll
        for (int i = 0; i < K_SP; ++i)
            out[(size_t)OUT_COEFF + (size_t)a[i] * 32768 + p] = (float)x[i];
    }

    // ---- recon, z_dl_st ----
    double rc = 0.0;
    #pragma unroll
    for (int i = 0; i < K_SP; ++i)
        rc += x[i] * (double)Dt[(size_t)a[i] * 64 + lane];
    const float zd = (float)rc;
    out[(size_t)(b * 64 + lane) * 4096 + hw] = pe + (zd - pe);

    // ---- loss: wave reduce -> block partial ----
    const float df = zd - pe;
    double sq = (double)df * (double)df;
    #pragma unroll
    for (int off = 32; off > 0; off >>= 1)
        sq += __shfl_xor(sq, off);
    if (lane == 0) lsum[wave] = sq;
    __syncthreads();
    if (threadIdx.x == 0)
        lpart[blockIdx.x] = (lsum[0] + lsum[1]) + (lsum[2] + lsum[3]);
}

// ---------------- final loss reduction: 8192 f64 partials -> out[OUT_LOSS] ----
__global__ void loss_reduce(const double* __restrict__ lpart,
                            float* __restrict__ out) {
    __shared__ double ls[4];
    const int tid = threadIdx.x, wave = tid >> 6, lane = tid & 63;
    double s = 0.0;
    for (int i = tid; i < NBLOCKS_OMP; i += 256) s += lpart[i];
    #pragma unroll
    for (int off = 32; off > 0; off >>= 1)
        s += __shfl_xor(s, off);
    if (lane == 0) ls[wave] = s;
    __syncthreads();
    if (tid == 0)
        out[OUT_LOSS] = (float)(((ls[0] + ls[1]) + (ls[2] + ls[3])) * (1.25 / 2097152.0));
}

extern "C" void kernel_launch(void* const* d_in, const int* in_sizes, int n_in,
                              void* d_out, int out_size, void* d_ws, size_t ws_size,
                              hipStream_t stream) {
    const float* ze = (const float*)d_in[0];   // (8,64,64,64) f32
    const float* D  = (const float*)d_in[1];   // (64,512) f32, unit-norm cols
    float* out = (float*)d_out;

    const size_t H_BYTES  = (size_t)P_TOTAL * 512 * 4;   // 67108864 (f32)
    const size_t G_BYTES  = (size_t)512 * 512 * 8;       // 2097152
    const size_t GF_BYTES = (size_t)512 * 512 * 4;       // 1048576
    const size_t DT_BYTES = (size_t)512 * 64 * 4;        // 131072

    float*  H  = (float*)d_ws;
    double* G  = (double*)((char*)d_ws + H_BYTES);
    float*  Gf = (float*)((char*)d_ws + H_BYTES + G_BYTES);
    float*  Dt = (float*)((char*)d_ws + H_BYTES + G_BYTES + GF_BYTES);
    double* LP = (double*)((char*)d_ws + H_BYTES + G_BYTES + GF_BYTES + DT_BYTES);

    setup_kernel<<<SETUP_BLOCKS, 256, 0, stream>>>(ze, D, out, G, Gf, Dt, H);
    omp2_kernel<<<NBLOCKS_OMP, 256, 0, stream>>>(ze, H, G, Gf, Dt, out, LP);
    loss_reduce<<<1, 256, 0, stream>>>(LP, out);
}